// Round 7
// baseline (181.635 us; speedup 1.0000x reference)
//
#include <hip/hip_runtime.h>
#include <hip/hip_bf16.h>

typedef short short8 __attribute__((ext_vector_type(8)));
typedef short short4v __attribute__((ext_vector_type(4)));
typedef float f32x4 __attribute__((ext_vector_type(4)));

// Problem constants: B=2, T=2048, E=1024, H=16, D=64

__device__ __forceinline__ short bf16r(float f) {
  unsigned int u = __builtin_bit_cast(unsigned int, f);
  unsigned int r = (u + 0x7fffu + ((u >> 16) & 1u)) >> 16;   // RNE
  return (short)r;
}

__device__ __forceinline__ unsigned int cvtpk(float a, float b) {
  unsigned int r;
  asm("v_cvt_pk_bf16_f32 %0, %1, %2" : "=v"(r) : "v"(a), "v"(b));
  return r;
}

__device__ __forceinline__ float fast_exp2(float x) {
  return __builtin_amdgcn_exp2f(x);
}

__device__ __forceinline__ void gload_lds16(const void* g, void* l) {
  __builtin_amdgcn_global_load_lds(
      (const __attribute__((address_space(1))) unsigned int*)g,
      (__attribute__((address_space(3))) unsigned int*)l, 16, 0, 0);
}

// ---------------- fused prep: x->bf16, W->bf16, rope table ----------------
__global__ void prep_k(const float* __restrict__ x, const float* __restrict__ W,
                       short* __restrict__ xb, short* __restrict__ wb,
                       float2* __restrict__ tab) {
  int gid = blockIdx.x * 256 + threadIdx.x;
  if (gid < 1048576) {                       // x: 4194304 f32 as float4
    float4 v = reinterpret_cast<const float4*>(x)[gid];
    short4v o = { bf16r(v.x), bf16r(v.y), bf16r(v.z), bf16r(v.w) };
    reinterpret_cast<short4v*>(xb)[gid] = o;
  } else if (gid < 1835008) {                // W: 3145728 f32
    int i = gid - 1048576;
    float4 v = reinterpret_cast<const float4*>(W)[i];
    short4v o = { bf16r(v.x), bf16r(v.y), bf16r(v.z), bf16r(v.w) };
    reinterpret_cast<short4v*>(wb)[i] = o;
  } else if (gid < 1900544) {                // rope table: 2048*32
    int idx = gid - 1835008;
    int t = idx >> 5, j = idx & 31;
    float freq = 1.0f / powf(10000.0f, (float)j * (1.0f / 32.0f));
    float ang = (float)t * freq;
    tab[idx] = make_float2(cosf(ang), sinf(ang));
  }
}

// ---------------- QKV GEMM: C[4096,3072] = x @ W^T + b, fused RoPE + scatter ----------------
// 128x64 tile, BK=64, DOUBLE-buffered with counted vmcnt (never 0 in loop): 48KB LDS, 3 blocks/CU.
// Grid 32 tm x 48 tn = 1536 blocks = exactly 2 rounds at 3/CU.
// q -> [bh][t][d] bf16 pre-scaled by (1/8)*log2(e); k -> [bh][t][d]; v -> [bh][d][t] transposed.
__launch_bounds__(256, 3)
__global__ void qkv_gemm_k(const short* __restrict__ xb, const short* __restrict__ wb,
                           const float* __restrict__ bias, const float2* __restrict__ tab,
                           short* __restrict__ qb, short* __restrict__ kb, short* __restrict__ vb) {
  __shared__ short lsm[24576];               // 48 KB: 2 x (A 8192 + B 4096 shorts); lT in V epilogue
  const int tid = threadIdx.x;
  const int l = tid & 63, w = tid >> 6;
  const int wr = w >> 1, wc = w & 1;
  const int l15 = l & 15, lg = l >> 4;

  int bid = blockIdx.x;
  int swz = (bid & 7) * 192 + (bid >> 3);  // 1536 blocks, bijective XCD swizzle
  int tm = swz / 48, tn = swz % 48;

  f32x4 acc[4][2] = {};

  auto stage = [&](int buf, int kt) {       // 6 loads/thread: A(4) + B(2)
    const int k0 = kt * 64;
    short* lA = lsm + buf * 12288;
    short* lB = lA + 8192;
#pragma unroll
    for (int p = 0; p < 4; ++p) {
      int idx = p * 256 + tid;
      int row = idx >> 3, ch = idx & 7;
      int gch = ch ^ (row & 7);
      gload_lds16(xb + (tm * 128 + row) * 1024 + k0 + gch * 8, (char*)lA + idx * 16);
    }
#pragma unroll
    for (int p = 0; p < 2; ++p) {
      int idx = p * 256 + tid;
      int row = idx >> 3, ch = idx & 7;
      int gch = ch ^ (row & 7);
      gload_lds16(wb + (tn * 64 + row) * 1024 + k0 + gch * 8, (char*)lB + idx * 16);
    }
  };

  stage(0, 0);
  stage(1, 1);

  for (int kt = 0; kt < 16; ++kt) {
    const int cur = kt & 1;
    if (kt + 1 < 16) asm volatile("s_waitcnt vmcnt(6)" ::: "memory");
    else             asm volatile("s_waitcnt vmcnt(0)" ::: "memory");
    __builtin_amdgcn_sched_barrier(0);
    __builtin_amdgcn_s_barrier();            // all waves' tile-kt loads landed
    __builtin_amdgcn_sched_barrier(0);

    const char* la = (const char*)(lsm + cur * 12288);
    const char* lb = la + 16384;
#pragma unroll
    for (int kc = 0; kc < 2; ++kc) {
      short8 af[4], bfr[2];
#pragma unroll
      for (int m = 0; m < 4; ++m) {
        int row = wr * 64 + m * 16 + l15;
        int ch = (kc * 4 + lg) ^ (row & 7);
        af[m] = *reinterpret_cast<const short8*>(la + row * 128 + ch * 16);
      }
#pragma unroll
      for (int n = 0; n < 2; ++n) {
        int row = wc * 32 + n * 16 + l15;
        int ch = (kc * 4 + lg) ^ (row & 7);
        bfr[n] = *reinterpret_cast<const short8*>(lb + row * 128 + ch * 16);
      }
#pragma unroll
      for (int m = 0; m < 4; ++m)
#pragma unroll
        for (int n = 0; n < 2; ++n)
          acc[m][n] = __builtin_amdgcn_mfma_f32_16x16x32_bf16(af[m], bfr[n], acc[m][n], 0, 0, 0);
    }
    __builtin_amdgcn_sched_barrier(0);
    __builtin_amdgcn_s_barrier();            // all waves done reading buf cur
    __builtin_amdgcn_sched_barrier(0);
    if (kt < 14) stage(cur, kt + 2);         // overwrite cur with tile kt+2 (in flight over next iter)
  }

  const int sec = tn >> 4;   // 16 tiles per 1024-col section: 0=q 1=k 2=v
  if (sec == 2) {
    // ---- V: transpose 128t x 64d tile through LDS -> contiguous [bh][d][t] writes ----
    __syncthreads();                          // all waves done with lsm
    short* lT = lsm;                          // [64 d][136 t-stride] (272B rows, 16B-aligned)
#pragma unroll
    for (int m = 0; m < 4; ++m)
#pragma unroll
      for (int n = 0; n < 2; ++n) {
        int d_local = wc * 32 + n * 16 + l15;
        int t_local = wr * 64 + m * 16 + lg * 4;
        float bv = bias[tn * 64 + d_local];
        f32x4 v = acc[m][n];
        short4v sv = { bf16r(v[0] + bv), bf16r(v[1] + bv), bf16r(v[2] + bv), bf16r(v[3] + bv) };
        *reinterpret_cast<short4v*>(lT + d_local * 136 + t_local) = sv;
      }
    __syncthreads();
    int row = tid >> 2;                       // d 0..63
    int toff = (tid & 3) * 32;                // 32 t-values per thread
    int h = tn & 15;                          // one head per v-tile
    int bb = tm >> 4;
    int t0 = (tm * 128) & 2047;
    short* dst = vb + (((bb * 16 + h) * 64 + row) * 2048) + t0 + toff;
    const short* srcl = lT + row * 136 + toff;
#pragma unroll
    for (int c = 0; c < 4; ++c)
      *reinterpret_cast<short8*>(dst + c * 8) = *reinterpret_cast<const short8*>(srcl + c * 8);
  } else {
    // ---- Q/K: bias + RoPE + scatter ----
    short* dst = (sec == 0) ? qb : kb;
    float scale = (sec == 0) ? 0.18033688f : 1.0f;  // (1/8)*log2e folded into q
#pragma unroll
    for (int m = 0; m < 4; ++m) {
#pragma unroll
      for (int n = 0; n < 2; ++n) {
        int gcol = tn * 64 + wc * 32 + n * 16 + l15;
        float bv = bias[gcol];
        int colin = gcol & 1023;
        int h = colin >> 6, d = colin & 63;
        int j = d >> 1;
        bool odd = d & 1;
        f32x4 v = acc[m][n];
#pragma unroll
        for (int i = 0; i < 4; ++i) v[i] += bv;
        int rbase = tm * 128 + wr * 64 + m * 16 + lg * 4;
#pragma unroll
        for (int i = 0; i < 4; ++i) {
          int grow = rbase + i;
          int t = grow & 2047;
          float2 cs = tab[t * 32 + j];
          float part = __shfl_xor(v[i], 1);
          float nv = odd ? (cs.y * part + cs.x * v[i]) : (cs.x * v[i] - cs.y * part);
          int b = grow >> 11;
          dst[(((b * 16 + h) * 2048 + t) << 6) + d] = bf16r(nv * scale);
        }
      }
    }
  }
}

// ---------------- Flash attention, swapped-QK^T, counted-vmcnt pipeline ----------------
// 4 waves x 16 q-rows = 64 q/block; KVBLK=64 double-buffered, prefetch depth 2 tiles.
// Grid 1024: XCD (id&7) owns bh in [4*xcd, 4*xcd+4) (KV stays L2-resident, proven R6).
__launch_bounds__(256, 4)
__global__ void attn_k(const short* __restrict__ qb, const short* __restrict__ kb,
                       const short* __restrict__ vtb, float* __restrict__ out) {
  __shared__ short lK[2][64 * 64];    // [kv][d], chunk-XOR swizzled via source
  __shared__ short lVT[2][64 * 64];   // [d][kv], chunk-XOR swizzled via source
  __shared__ short lP[4][16 * 64];    // per-wave P^T as [q][kv], chunk-XOR swizzled
  const int tid = threadIdx.x, l = tid & 63, w = tid >> 6;
  const int l15 = l & 15, lg = l >> 4;

  const int id = blockIdx.x;
  const int bh = (id & 7) * 4 + ((id >> 3) & 3);
  const int qt = id >> 5;

  const short* kbase = kb + bh * 2048 * 64;
  const short* vtbase = vtb + bh * 64 * 2048;

  // staging addresses (per-thread, hoisted)
  const int srow = tid >> 3, sch = tid & 7;
  const int gch = sch ^ (srow & 7);
  const short* ksrc = kbase + srow * 64 + gch * 8;     // +kt*4096
  const short* vsrc = vtbase + srow * 2048 + gch * 8;  // +kt*64

  auto stageKV = [&](int buf, int kt) {                // 4 loads/thread
    gload_lds16(ksrc + kt * 4096, (char*)lK[buf] + tid * 16);
    gload_lds16(ksrc + kt * 4096 + 2048, (char*)lK[buf] + 4096 + tid * 16);
    gload_lds16(vsrc + kt * 64, (char*)lVT[buf] + tid * 16);
    gload_lds16(vsrc + kt * 64 + 32 * 2048, (char*)lVT[buf] + 4096 + tid * 16);
  };

  // Q B-frag first (oldest vmcnt entries; forced complete by iter-0 wait)
  const int q = qt * 64 + w * 16 + l15;
  const short* qptr = qb + (bh * 2048 + q) * 64;
  short8 qf[2];
  qf[0] = *reinterpret_cast<const short8*>(qptr + lg * 8);
  qf[1] = *reinterpret_cast<const short8*>(qptr + 32 + lg * 8);

  stageKV(0, 0);
  stageKV(1, 1);

  f32x4 o[4] = {};
  float mval = -1e30f, lval = 0.f;
  char* pw = (char*)lP[w];
  const int pbase = l15 * 128;

  for (int kt = 0; kt < 32; ++kt) {
    const int cur = kt & 1;
    if (kt + 1 < 32) asm volatile("s_waitcnt vmcnt(4)" ::: "memory");
    else             asm volatile("s_waitcnt vmcnt(0)" ::: "memory");
    __builtin_amdgcn_sched_barrier(0);
    __builtin_amdgcn_s_barrier();            // all waves' tile-kt loads landed
    __builtin_amdgcn_sched_barrier(0);

    const char* lk = (const char*)lK[cur];
    const char* lv = (const char*)lVT[cur];

    // S^T[kv][q] : A = K tile (4 m-subtiles), B = Q
    f32x4 s[4] = {};
    __builtin_amdgcn_s_setprio(1);
#pragma unroll
    for (int kc = 0; kc < 2; ++kc)
#pragma unroll
      for (int m = 0; m < 4; ++m) {
        int row = m * 16 + l15;
        short8 kf = *reinterpret_cast<const short8*>(lk + row * 128 + (((kc * 4 + lg) ^ (row & 7)) * 16));
        s[m] = __builtin_amdgcn_mfma_f32_16x16x32_bf16(kf, qf[kc], s[m], 0, 0, 0);
      }
    __builtin_amdgcn_s_setprio(0);

    // row max: tree reduce (depth 4) + 2 shuffles (lane owns q = l15)
    float a0 = fmaxf(fmaxf(s[0][0], s[0][1]), fmaxf(s[0][2], s[0][3]));
    float a1 = fmaxf(fmaxf(s[1][0], s[1][1]), fmaxf(s[1][2], s[1][3]));
    float a2 = fmaxf(fmaxf(s[2][0], s[2][1]), fmaxf(s[2][2], s[2][3]));
    float a3 = fmaxf(fmaxf(s[3][0], s[3][1]), fmaxf(s[3][2], s[3][3]));
    float rm = fmaxf(fmaxf(a0, a1), fmaxf(a2, a3));
    rm = fmaxf(rm, __shfl_xor(rm, 16));
    rm = fmaxf(rm, __shfl_xor(rm, 32));

    // defer-max (T13): only rescale when some row grew by > 8 (log2 units)
    if (!__all(rm <= mval + 8.0f)) {
      float mn = fmaxf(mval, rm);
      float corr = fast_exp2(mval - mn);
      mval = mn;
      lval *= corr;
#pragma unroll
      for (int dt = 0; dt < 4; ++dt)
#pragma unroll
        for (int i = 0; i < 4; ++i) o[dt][i] *= corr;
    }

    // P = 2^(S - m); tree row sum
#pragma unroll
    for (int m = 0; m < 4; ++m)
#pragma unroll
      for (int i = 0; i < 4; ++i)
        s[m][i] = fast_exp2(s[m][i] - mval);
    float b0 = (s[0][0] + s[0][1]) + (s[0][2] + s[0][3]);
    float b1 = (s[1][0] + s[1][1]) + (s[1][2] + s[1][3]);
    float b2 = (s[2][0] + s[2][1]) + (s[2][2] + s[2][3]);
    float b3 = (s[3][0] + s[3][1]) + (s[3][2] + s[3][3]);
    float rs = (b0 + b1) + (b2 + b3);
    rs += __shfl_xor(rs, 16);
    rs += __shfl_xor(rs, 32);
    lval += rs;

    // pack bf16 pairs (HW cvt_pk) -> per-wave P^T[q][kv] (u32 writes, chunk-XOR swizzle)
#pragma unroll
    for (int m = 0; m < 4; ++m)
#pragma unroll
      for (int j = 0; j < 2; ++j) {
        unsigned int v32 = cvtpk(s[m][2 * j], s[m][2 * j + 1]);
        int kv = m * 16 + lg * 4 + 2 * j;
        *reinterpret_cast<unsigned int*>(
            pw + pbase + (((kv >> 3) ^ (l15 & 7)) * 16) + ((kv & 7) * 2)) = v32;
      }

    // O^T += V^T P^T
    __builtin_amdgcn_s_setprio(1);
#pragma unroll
    for (int kc = 0; kc < 2; ++kc) {
      short8 pf = *reinterpret_cast<const short8*>(
          pw + pbase + (((kc * 4 + lg) ^ (l15 & 7)) * 16));
#pragma unroll
      for (int dt = 0; dt < 4; ++dt) {
        int row = dt * 16 + l15;
        short8 vf = *reinterpret_cast<const short8*>(lv + row * 128 + (((kc * 4 + lg) ^ (row & 7)) * 16));
        o[dt] = __builtin_amdgcn_mfma_f32_16x16x32_bf16(vf, pf, o[dt], 0, 0, 0);
      }
    }
    __builtin_amdgcn_s_setprio(0);

    __builtin_amdgcn_sched_barrier(0);
    __builtin_amdgcn_s_barrier();            // all waves done reading buf cur
    __builtin_amdgcn_sched_barrier(0);
    if (kt < 30) stageKV(cur, kt + 2);       // overwrite cur; lands during next iter
  }

  // epilogue: O^T C-frag col=q, row=d -> float4 stores
  float inv = 1.0f / lval;
  const int b = bh >> 4, h = bh & 15;
  float* op = out + ((b * 2048 + q) * 1024) + h * 64;
#pragma unroll
  for (int dt = 0; dt < 4; ++dt) {
    f32x4 r = { o[dt][0] * inv, o[dt][1] * inv, o[dt][2] * inv, o[dt][3] * inv };
    *reinterpret_cast<f32x4*>(op + dt * 16 + lg * 4) = r;
  }
}

// ---------------- launch ----------------
extern "C" void kernel_launch(void* const* d_in, const int* in_sizes, int n_in,
                              void* d_out, int out_size, void* d_ws, size_t ws_size,
                              hipStream_t stream) {
  const float* x    = (const float*)d_in[0];   // [2,2048,1024]
  const float* W    = (const float*)d_in[1];   // [3072,1024]
  const float* bias = (const float*)d_in[2];   // [3072]
  float* out = (float*)d_out;
  char* ws = (char*)d_ws;

  short*  xb   = (short*) (ws);                  //  8 MiB
  short*  wb   = (short*) (ws + 8388608);        //  6 MiB
  short*  qbuf = (short*) (ws + 14680064);       //  8 MiB q [bh][t][d] (pre-scaled)
  short*  kbuf = (short*) (ws + 23068672);       //  8 MiB k [bh][t][d]
  short*  vtbuf= (short*) (ws + 31457280);       //  8 MiB v TRANSPOSED [bh][d][t]
  float2* tab  = (float2*)(ws + 39845888);       //  512 KiB

  hipLaunchKernelGGL(prep_k, dim3(7424), dim3(256), 0, stream, x, W, xb, wb, tab);
  hipLaunchKernelGGL(qkv_gemm_k, dim3(1536), dim3(256), 0, stream,
                     xb, wb, bias, tab, qbuf, kbuf, vtbuf);
  hipLaunchKernelGGL(attn_k, dim3(1024), dim3(256), 0, stream, qbuf, kbuf, vtbuf, out);
}

// Round 9
// 167.071 us; speedup vs baseline: 1.0872x; 1.0872x over previous
//
#include <hip/hip_runtime.h>
#include <hip/hip_bf16.h>

typedef short short8 __attribute__((ext_vector_type(8)));
typedef short short4v __attribute__((ext_vector_type(4)));
typedef float f32x4 __attribute__((ext_vector_type(4)));

// Problem constants: B=2, T=2048, E=1024, H=16, D=64

__device__ __forceinline__ short bf16r(float f) {
  unsigned int u = __builtin_bit_cast(unsigned int, f);
  unsigned int r = (u + 0x7fffu + ((u >> 16) & 1u)) >> 16;   // RNE
  return (short)r;
}

__device__ __forceinline__ unsigned int cvtpk(float a, float b) {
  unsigned int r;
  asm("v_cvt_pk_bf16_f32 %0, %1, %2" : "=v"(r) : "v"(a), "v"(b));
  return r;
}

__device__ __forceinline__ float fast_exp2(float x) {
  return __builtin_amdgcn_exp2f(x);
}

__device__ __forceinline__ void gload_lds16(const void* g, void* l) {
  __builtin_amdgcn_global_load_lds(
      (const __attribute__((address_space(1))) unsigned int*)g,
      (__attribute__((address_space(3))) unsigned int*)l, 16, 0, 0);
}

// ---------------- fused prep: x->bf16, W->bf16, rope table ----------------
__global__ void prep_k(const float* __restrict__ x, const float* __restrict__ W,
                       short* __restrict__ xb, short* __restrict__ wb,
                       float2* __restrict__ tab) {
  int gid = blockIdx.x * 256 + threadIdx.x;
  if (gid < 1048576) {                       // x: 4194304 f32 as float4
    float4 v = reinterpret_cast<const float4*>(x)[gid];
    short4v o = { bf16r(v.x), bf16r(v.y), bf16r(v.z), bf16r(v.w) };
    reinterpret_cast<short4v*>(xb)[gid] = o;
  } else if (gid < 1835008) {                // W: 3145728 f32
    int i = gid - 1048576;
    float4 v = reinterpret_cast<const float4*>(W)[i];
    short4v o = { bf16r(v.x), bf16r(v.y), bf16r(v.z), bf16r(v.w) };
    reinterpret_cast<short4v*>(wb)[i] = o;
  } else if (gid < 1900544) {                // rope table: 2048*32
    int idx = gid - 1835008;
    int t = idx >> 5, j = idx & 31;
    float freq = 1.0f / powf(10000.0f, (float)j * (1.0f / 32.0f));
    float ang = (float)t * freq;
    tab[idx] = make_float2(cosf(ang), sinf(ang));
  }
}

// ---------------- QKV GEMM (R6-proven): 128x128 tile, single-buffered, fused RoPE + scatter ----
__launch_bounds__(256, 3)
__global__ void qkv_gemm_k(const short* __restrict__ xb, const short* __restrict__ wb,
                           const float* __restrict__ bias, const float2* __restrict__ tab,
                           short* __restrict__ qb, short* __restrict__ kb, short* __restrict__ vb) {
  __shared__ short lsm[17408];               // 34 KB: lA | lB during loop, lT[128][136] in V epilogue
  short* lA = lsm;
  short* lB = lsm + 8192;
  const int tid = threadIdx.x;
  const int l = tid & 63, w = tid >> 6;
  const int wr = w >> 1, wc = w & 1;
  const int l15 = l & 15, lg = l >> 4;

  int bid = blockIdx.x;
  int swz = (bid & 7) * 96 + (bid >> 3);   // 768 blocks, bijective XCD swizzle
  int tm = swz / 24, tn = swz % 24;

  f32x4 acc[4][4] = {};

  for (int kt = 0; kt < 16; ++kt) {
    const int k0 = kt * 64;
    __syncthreads();
#pragma unroll
    for (int p = 0; p < 4; ++p) {
      int idx = p * 256 + tid;
      int row = idx >> 3, ch = idx & 7;
      int gch = ch ^ (row & 7);
      gload_lds16(xb + (tm * 128 + row) * 1024 + k0 + gch * 8, (char*)lA + idx * 16);
    }
#pragma unroll
    for (int p = 0; p < 4; ++p) {
      int idx = p * 256 + tid;
      int row = idx >> 3, ch = idx & 7;
      int gch = ch ^ (row & 7);
      gload_lds16(wb + (tn * 128 + row) * 1024 + k0 + gch * 8, (char*)lB + idx * 16);
    }
    __syncthreads();
#pragma unroll
    for (int kc = 0; kc < 2; ++kc) {
      short8 af[4], bfr[4];
#pragma unroll
      for (int m = 0; m < 4; ++m) {
        int row = wr * 64 + m * 16 + l15;
        int ch = (kc * 4 + lg) ^ (row & 7);
        af[m] = *reinterpret_cast<const short8*>((const char*)lA + row * 128 + ch * 16);
      }
#pragma unroll
      for (int n = 0; n < 4; ++n) {
        int row = wc * 64 + n * 16 + l15;
        int ch = (kc * 4 + lg) ^ (row & 7);
        bfr[n] = *reinterpret_cast<const short8*>((const char*)lB + row * 128 + ch * 16);
      }
#pragma unroll
      for (int m = 0; m < 4; ++m)
#pragma unroll
        for (int n = 0; n < 4; ++n)
          acc[m][n] = __builtin_amdgcn_mfma_f32_16x16x32_bf16(af[m], bfr[n], acc[m][n], 0, 0, 0);
    }
  }

  const int sec = tn >> 3;   // 0=q 1=k 2=v (block-uniform)
  if (sec == 2) {
    // ---- V: transpose tile through LDS, then contiguous writes to [bh][d][t] ----
    __syncthreads();
    short* lT = lsm;                          // [128 d][136 t-stride]
#pragma unroll
    for (int m = 0; m < 4; ++m)
#pragma unroll
      for (int n = 0; n < 4; ++n) {
        int d_local = wc * 64 + n * 16 + l15;
        int t_local = wr * 64 + m * 16 + lg * 4;
        float bv = bias[tn * 128 + d_local];
        f32x4 v = acc[m][n];
        short4v sv = { bf16r(v[0] + bv), bf16r(v[1] + bv), bf16r(v[2] + bv), bf16r(v[3] + bv) };
        *reinterpret_cast<short4v*>(lT + d_local * 136 + t_local) = sv;
      }
    __syncthreads();
    int row = tid >> 1;                       // d_local 0..127
    int tp = (tid & 1) * 64;                  // t half (64 t-values per thread)
    int h = (tn & 7) * 2 + (row >> 6);
    int d = row & 63;
    int bb = tm >> 4;
    int t0 = (tm * 128) & 2047;
    short* dst = vb + (((bb * 16 + h) * 64 + d) * 2048) + t0 + tp;
    const short* srcl = lT + row * 136 + tp;
#pragma unroll
    for (int c = 0; c < 8; ++c)
      *reinterpret_cast<short8*>(dst + c * 8) = *reinterpret_cast<const short8*>(srcl + c * 8);
  } else {
    // ---- Q/K: bias + RoPE + scatter ----
    short* dst = (sec == 0) ? qb : kb;
    float scale = (sec == 0) ? 0.18033688f : 1.0f;  // (1/8)*log2e folded into q
#pragma unroll
    for (int m = 0; m < 4; ++m) {
#pragma unroll
      for (int n = 0; n < 4; ++n) {
        int gcol = tn * 128 + wc * 64 + n * 16 + l15;
        float bv = bias[gcol];
        int colin = gcol & 1023;
        int h = colin >> 6, d = colin & 63;
        int j = d >> 1;
        bool odd = d & 1;
        f32x4 v = acc[m][n];
#pragma unroll
        for (int i = 0; i < 4; ++i) v[i] += bv;
        int rbase = tm * 128 + wr * 64 + m * 16 + lg * 4;
#pragma unroll
        for (int i = 0; i < 4; ++i) {
          int grow = rbase + i;
          int t = grow & 2047;
          float2 cs = tab[t * 32 + j];
          float part = __shfl_xor(v[i], 1);
          float nv = odd ? (cs.y * part + cs.x * v[i]) : (cs.x * v[i] - cs.y * part);
          int b = grow >> 11;
          dst[(((b * 16 + h) * 2048 + t) << 6) + d] = bf16r(nv * scale);
        }
      }
    }
  }
}

// ---------------- Flash attention: swapped-QK^T + T15 double-pipeline ----------------
// Per tile kt: QK^T(kt+1) MFMAs issue first (matrix pipe), softmax(kt) runs on VALU in
// parallel (previous tile's in-register scores), then PV(kt).
// K/V double-buffered, counted vmcnt(2) at entry (= V(kt) + K(kt+1) retired, V(kt+1) in flight).
// Reductions: __shfl_xor (proven R2-R7; permlane asm was R8's correctness bug).
__launch_bounds__(256, 4)
__global__ void attn_k(const short* __restrict__ qb, const short* __restrict__ kb,
                       const short* __restrict__ vtb, float* __restrict__ out) {
  __shared__ short lK[2][64 * 64];    // [kv][d], chunk-XOR swizzled via source
  __shared__ short lVT[2][64 * 64];   // [d][kv], chunk-XOR swizzled via source
  __shared__ short lP[4][16 * 64];    // per-wave P^T as [q][kv], chunk-XOR swizzled
  const int tid = threadIdx.x, l = tid & 63, w = tid >> 6;
  const int l15 = l & 15, lg = l >> 4;

  const int id = blockIdx.x;
  const int bh = (id & 7) * 4 + ((id >> 3) & 3);
  const int qt = id >> 5;

  const short* kbase = kb + bh * 2048 * 64;
  const short* vtbase = vtb + bh * 64 * 2048;

  const int srow = tid >> 3, sch = tid & 7;
  const int gch = sch ^ (srow & 7);
  const short* ksrc = kbase + srow * 64 + gch * 8;     // +kt*4096
  const short* vsrc = vtbase + srow * 2048 + gch * 8;  // +kt*64

  auto stageKV = [&](int buf, int kt) {                // 4 loads/thread: K,K,V,V
    gload_lds16(ksrc + kt * 4096, (char*)lK[buf] + tid * 16);
    gload_lds16(ksrc + kt * 4096 + 2048, (char*)lK[buf] + 4096 + tid * 16);
    gload_lds16(vsrc + kt * 64, (char*)lVT[buf] + tid * 16);
    gload_lds16(vsrc + kt * 64 + 32 * 2048, (char*)lVT[buf] + 4096 + tid * 16);
  };

  // Q B-frag (lane l15 = q column), q pre-scaled by log2e/8
  const int q = qt * 64 + w * 16 + l15;
  const short* qptr = qb + (bh * 2048 + q) * 64;
  short8 qf[2];
  qf[0] = *reinterpret_cast<const short8*>(qptr + lg * 8);
  qf[1] = *reinterpret_cast<const short8*>(qptr + 32 + lg * 8);

  stageKV(0, 0);
  stageKV(1, 1);

  f32x4 o[4] = {};
  f32x4 sA[4] = {}, sB[4];
  float mval = -1e30f, lval = 0.f;
  char* pw = (char*)lP[w];
  const int pbase = l15 * 128;

  // prologue: QK(0) -> sA
  asm volatile("s_waitcnt vmcnt(6)" ::: "memory");
  __builtin_amdgcn_sched_barrier(0);
  __builtin_amdgcn_s_barrier();
  __builtin_amdgcn_sched_barrier(0);
  {
    const char* lk = (const char*)lK[0];
#pragma unroll
    for (int kc = 0; kc < 2; ++kc)
#pragma unroll
      for (int m = 0; m < 4; ++m) {
        int row = m * 16 + l15;
        short8 kf = *reinterpret_cast<const short8*>(lk + row * 128 + (((kc * 4 + lg) ^ (row & 7)) * 16));
        sA[m] = __builtin_amdgcn_mfma_f32_16x16x32_bf16(kf, qf[kc], sA[m], 0, 0, 0);
      }
  }

  auto tile = [&](int kt, f32x4 (&sC)[4], f32x4 (&sN)[4]) {
    // entry: wait V(kt) + K(kt+1) (oldest pairs), leave V(kt+1) in flight
    if (kt == 31) asm volatile("s_waitcnt vmcnt(0)" ::: "memory");
    else          asm volatile("s_waitcnt vmcnt(2)" ::: "memory");
    __builtin_amdgcn_sched_barrier(0);
    __builtin_amdgcn_s_barrier();
    __builtin_amdgcn_sched_barrier(0);

    // QK^T(kt+1) -> sN : matrix pipe, independent of softmax below
    if (kt + 1 < 32) {
      const char* lk = (const char*)lK[(kt + 1) & 1];
      __builtin_amdgcn_s_setprio(1);
#pragma unroll
      for (int m = 0; m < 4; ++m) sN[m] = (f32x4){};
#pragma unroll
      for (int kc = 0; kc < 2; ++kc)
#pragma unroll
        for (int m = 0; m < 4; ++m) {
          int row = m * 16 + l15;
          short8 kf = *reinterpret_cast<const short8*>(lk + row * 128 + (((kc * 4 + lg) ^ (row & 7)) * 16));
          sN[m] = __builtin_amdgcn_mfma_f32_16x16x32_bf16(kf, qf[kc], sN[m], 0, 0, 0);
        }
      __builtin_amdgcn_s_setprio(0);
    }

    // softmax(sC) — VALU overlapping the QK MFMAs above
    float a0 = fmaxf(fmaxf(sC[0][0], sC[0][1]), fmaxf(sC[0][2], sC[0][3]));
    float a1 = fmaxf(fmaxf(sC[1][0], sC[1][1]), fmaxf(sC[1][2], sC[1][3]));
    float a2 = fmaxf(fmaxf(sC[2][0], sC[2][1]), fmaxf(sC[2][2], sC[2][3]));
    float a3 = fmaxf(fmaxf(sC[3][0], sC[3][1]), fmaxf(sC[3][2], sC[3][3]));
    float rm = fmaxf(fmaxf(a0, a1), fmaxf(a2, a3));
    rm = fmaxf(rm, __shfl_xor(rm, 16));
    rm = fmaxf(rm, __shfl_xor(rm, 32));

    if (!__all(rm <= mval + 8.0f)) {     // defer-max (T13)
      float mn = fmaxf(mval, rm);
      float corr = fast_exp2(mval - mn);
      mval = mn;
      lval *= corr;
#pragma unroll
      for (int dt = 0; dt < 4; ++dt)
#pragma unroll
        for (int i = 0; i < 4; ++i) o[dt][i] *= corr;
    }

#pragma unroll
    for (int m = 0; m < 4; ++m)
#pragma unroll
      for (int i = 0; i < 4; ++i)
        sC[m][i] = fast_exp2(sC[m][i] - mval);
    float b0 = (sC[0][0] + sC[0][1]) + (sC[0][2] + sC[0][3]);
    float b1 = (sC[1][0] + sC[1][1]) + (sC[1][2] + sC[1][3]);
    float b2 = (sC[2][0] + sC[2][1]) + (sC[2][2] + sC[2][3]);
    float b3 = (sC[3][0] + sC[3][1]) + (sC[3][2] + sC[3][3]);
    float rs = (b0 + b1) + (b2 + b3);
    rs += __shfl_xor(rs, 16);
    rs += __shfl_xor(rs, 32);
    lval += rs;

    // pack P -> per-wave LDS (C-frag -> A-frag relayout)
#pragma unroll
    for (int m = 0; m < 4; ++m)
#pragma unroll
      for (int j = 0; j < 2; ++j) {
        unsigned int v32 = cvtpk(sC[m][2 * j], sC[m][2 * j + 1]);
        int kv = m * 16 + lg * 4 + 2 * j;
        *reinterpret_cast<unsigned int*>(
            pw + pbase + (((kv >> 3) ^ (l15 & 7)) * 16) + ((kv & 7) * 2)) = v32;
      }

    // O^T += V^T(kt) P^T(kt)
    const char* lv = (const char*)lVT[kt & 1];
    __builtin_amdgcn_s_setprio(1);
#pragma unroll
    for (int kc = 0; kc < 2; ++kc) {
      short8 pf = *reinterpret_cast<const short8*>(
          pw + pbase + (((kc * 4 + lg) ^ (l15 & 7)) * 16));
#pragma unroll
      for (int dt = 0; dt < 4; ++dt) {
        int row = dt * 16 + l15;
        short8 vf = *reinterpret_cast<const short8*>(lv + row * 128 + (((kc * 4 + lg) ^ (row & 7)) * 16));
        o[dt] = __builtin_amdgcn_mfma_f32_16x16x32_bf16(vf, pf, o[dt], 0, 0, 0);
      }
    }
    __builtin_amdgcn_s_setprio(0);

    __builtin_amdgcn_sched_barrier(0);
    __builtin_amdgcn_s_barrier();            // all waves done with K(kt)/V(kt) buffers
    __builtin_amdgcn_sched_barrier(0);
    if (kt + 2 < 32) stageKV(kt & 1, kt + 2);  // overwrite just-freed buffer
  };

  for (int kt = 0; kt < 32; kt += 2) {
    tile(kt, sA, sB);
    tile(kt + 1, sB, sA);
  }

  // epilogue: O^T C-frag col=q, row=d -> float4 stores
  float inv = 1.0f / lval;
  const int b = bh >> 4, h = bh & 15;
  float* op = out + ((b * 2048 + q) * 1024) + h * 64;
#pragma unroll
  for (int dt = 0; dt < 4; ++dt) {
    f32x4 r = { o[dt][0] * inv, o[dt][1] * inv, o[dt][2] * inv, o[dt][3] * inv };
    *reinterpret_cast<f32x4*>(op + dt * 16 + lg * 4) = r;
  }
}

// ---------------- launch ----------------
extern "C" void kernel_launch(void* const* d_in, const int* in_sizes, int n_in,
                              void* d_out, int out_size, void* d_ws, size_t ws_size,
                              hipStream_t stream) {
  const float* x    = (const float*)d_in[0];   // [2,2048,1024]
  const float* W    = (const float*)d_in[1];   // [3072,1024]
  const float* bias = (const float*)d_in[2];   // [3072]
  float* out = (float*)d_out;
  char* ws = (char*)d_ws;

  short*  xb   = (short*) (ws);                  //  8 MiB
  short*  wb   = (short*) (ws + 8388608);        //  6 MiB
  short*  qbuf = (short*) (ws + 14680064);       //  8 MiB q [bh][t][d] (pre-scaled)
  short*  kbuf = (short*) (ws + 23068672);       //  8 MiB k [bh][t][d]
  short*  vtbuf= (short*) (ws + 31457280);       //  8 MiB v TRANSPOSED [bh][d][t]
  float2* tab  = (float2*)(ws + 39845888);       //  512 KiB

  hipLaunchKernelGGL(prep_k, dim3(7424), dim3(256), 0, stream, x, W, xb, wb, tab);
  hipLaunchKernelGGL(qkv_gemm_k, dim3(768), dim3(256), 0, stream,
                     xb, wb, bias, tab, qbuf, kbuf, vtbuf);
  hipLaunchKernelGGL(attn_k, dim3(1024), dim3(256), 0, stream, qbuf, kbuf, vtbuf, out);
}

// Round 10
// 166.418 us; speedup vs baseline: 1.0914x; 1.0039x over previous
//
#include <hip/hip_runtime.h>
#include <hip/hip_bf16.h>

typedef short short8 __attribute__((ext_vector_type(8)));
typedef short short4v __attribute__((ext_vector_type(4)));
typedef float f32x4 __attribute__((ext_vector_type(4)));

// Problem constants: B=2, T=2048, E=1024, H=16, D=64

__device__ __forceinline__ short bf16r(float f) {
  unsigned int u = __builtin_bit_cast(unsigned int, f);
  unsigned int r = (u + 0x7fffu + ((u >> 16) & 1u)) >> 16;   // RNE
  return (short)r;
}

__device__ __forceinline__ unsigned int cvtpk(float a, float b) {
  unsigned int r;
  asm("v_cvt_pk_bf16_f32 %0, %1, %2" : "=v"(r) : "v"(a), "v"(b));
  return r;
}

__device__ __forceinline__ float fast_exp2(float x) {
  return __builtin_amdgcn_exp2f(x);
}

__device__ __forceinline__ void gload_lds16(const void* g, void* l) {
  __builtin_amdgcn_global_load_lds(
      (const __attribute__((address_space(1))) unsigned int*)g,
      (__attribute__((address_space(3))) unsigned int*)l, 16, 0, 0);
}

// ---------------- fused prep: x->bf16, W->bf16, rope table ----------------
__global__ void prep_k(const float* __restrict__ x, const float* __restrict__ W,
                       short* __restrict__ xb, short* __restrict__ wb,
                       float2* __restrict__ tab) {
  int gid = blockIdx.x * 256 + threadIdx.x;
  if (gid < 1048576) {                       // x: 4194304 f32 as float4
    float4 v = reinterpret_cast<const float4*>(x)[gid];
    short4v o = { bf16r(v.x), bf16r(v.y), bf16r(v.z), bf16r(v.w) };
    reinterpret_cast<short4v*>(xb)[gid] = o;
  } else if (gid < 1835008) {                // W: 3145728 f32
    int i = gid - 1048576;
    float4 v = reinterpret_cast<const float4*>(W)[i];
    short4v o = { bf16r(v.x), bf16r(v.y), bf16r(v.z), bf16r(v.w) };
    reinterpret_cast<short4v*>(wb)[i] = o;
  } else if (gid < 1900544) {                // rope table: 2048*32
    int idx = gid - 1835008;
    int t = idx >> 5, j = idx & 31;
    float freq = 1.0f / powf(10000.0f, (float)j * (1.0f / 32.0f));
    float ang = (float)t * freq;
    tab[idx] = make_float2(cosf(ang), sinf(ang));
  }
}

// ---------------- QKV GEMM (R6-proven): 128x128 tile, single-buffered, fused RoPE + scatter ----
__launch_bounds__(256, 3)
__global__ void qkv_gemm_k(const short* __restrict__ xb, const short* __restrict__ wb,
                           const float* __restrict__ bias, const float2* __restrict__ tab,
                           short* __restrict__ qb, short* __restrict__ kb, short* __restrict__ vb) {
  __shared__ short lsm[17408];               // 34 KB: lA | lB during loop, lT[128][136] in V epilogue
  short* lA = lsm;
  short* lB = lsm + 8192;
  const int tid = threadIdx.x;
  const int l = tid & 63, w = tid >> 6;
  const int wr = w >> 1, wc = w & 1;
  const int l15 = l & 15, lg = l >> 4;

  int bid = blockIdx.x;
  int swz = (bid & 7) * 96 + (bid >> 3);   // 768 blocks, bijective XCD swizzle
  int tm = swz / 24, tn = swz % 24;

  f32x4 acc[4][4] = {};

  for (int kt = 0; kt < 16; ++kt) {
    const int k0 = kt * 64;
    __syncthreads();
#pragma unroll
    for (int p = 0; p < 4; ++p) {
      int idx = p * 256 + tid;
      int row = idx >> 3, ch = idx & 7;
      int gch = ch ^ (row & 7);
      gload_lds16(xb + (tm * 128 + row) * 1024 + k0 + gch * 8, (char*)lA + idx * 16);
    }
#pragma unroll
    for (int p = 0; p < 4; ++p) {
      int idx = p * 256 + tid;
      int row = idx >> 3, ch = idx & 7;
      int gch = ch ^ (row & 7);
      gload_lds16(wb + (tn * 128 + row) * 1024 + k0 + gch * 8, (char*)lB + idx * 16);
    }
    __syncthreads();
#pragma unroll
    for (int kc = 0; kc < 2; ++kc) {
      short8 af[4], bfr[4];
#pragma unroll
      for (int m = 0; m < 4; ++m) {
        int row = wr * 64 + m * 16 + l15;
        int ch = (kc * 4 + lg) ^ (row & 7);
        af[m] = *reinterpret_cast<const short8*>((const char*)lA + row * 128 + ch * 16);
      }
#pragma unroll
      for (int n = 0; n < 4; ++n) {
        int row = wc * 64 + n * 16 + l15;
        int ch = (kc * 4 + lg) ^ (row & 7);
        bfr[n] = *reinterpret_cast<const short8*>((const char*)lB + row * 128 + ch * 16);
      }
#pragma unroll
      for (int m = 0; m < 4; ++m)
#pragma unroll
        for (int n = 0; n < 4; ++n)
          acc[m][n] = __builtin_amdgcn_mfma_f32_16x16x32_bf16(af[m], bfr[n], acc[m][n], 0, 0, 0);
    }
  }

  const int sec = tn >> 3;   // 0=q 1=k 2=v (block-uniform)
  if (sec == 2) {
    // ---- V: transpose tile through LDS, then contiguous writes to [bh][d][t] ----
    __syncthreads();
    short* lT = lsm;                          // [128 d][136 t-stride]
#pragma unroll
    for (int m = 0; m < 4; ++m)
#pragma unroll
      for (int n = 0; n < 4; ++n) {
        int d_local = wc * 64 + n * 16 + l15;
        int t_local = wr * 64 + m * 16 + lg * 4;
        float bv = bias[tn * 128 + d_local];
        f32x4 v = acc[m][n];
        short4v sv = { bf16r(v[0] + bv), bf16r(v[1] + bv), bf16r(v[2] + bv), bf16r(v[3] + bv) };
        *reinterpret_cast<short4v*>(lT + d_local * 136 + t_local) = sv;
      }
    __syncthreads();
    int row = tid >> 1;                       // d_local 0..127
    int tp = (tid & 1) * 64;                  // t half (64 t-values per thread)
    int h = (tn & 7) * 2 + (row >> 6);
    int d = row & 63;
    int bb = tm >> 4;
    int t0 = (tm * 128) & 2047;
    short* dst = vb + (((bb * 16 + h) * 64 + d) * 2048) + t0 + tp;
    const short* srcl = lT + row * 136 + tp;
#pragma unroll
    for (int c = 0; c < 8; ++c)
      *reinterpret_cast<short8*>(dst + c * 8) = *reinterpret_cast<const short8*>(srcl + c * 8);
  } else {
    // ---- Q/K: bias + RoPE + scatter ----
    short* dst = (sec == 0) ? qb : kb;
    float scale = (sec == 0) ? 0.18033688f : 1.0f;  // (1/8)*log2e folded into q
#pragma unroll
    for (int m = 0; m < 4; ++m) {
#pragma unroll
      for (int n = 0; n < 4; ++n) {
        int gcol = tn * 128 + wc * 64 + n * 16 + l15;
        float bv = bias[gcol];
        int colin = gcol & 1023;
        int h = colin >> 6, d = colin & 63;
        int j = d >> 1;
        bool odd = d & 1;
        f32x4 v = acc[m][n];
#pragma unroll
        for (int i = 0; i < 4; ++i) v[i] += bv;
        int rbase = tm * 128 + wr * 64 + m * 16 + lg * 4;
#pragma unroll
        for (int i = 0; i < 4; ++i) {
          int grow = rbase + i;
          int t = grow & 2047;
          float2 cs = tab[t * 32 + j];
          float part = __shfl_xor(v[i], 1);
          float nv = odd ? (cs.y * part + cs.x * v[i]) : (cs.x * v[i] - cs.y * part);
          int b = grow >> 11;
          dst[(((b * 16 + h) * 2048 + t) << 6) + d] = bf16r(nv * scale);
        }
      }
    }
  }
}

// ---------------- Flash attention: swapped-QK^T, VALU-lean softmax ----------------
// Sum via ones-MFMA (denominator = exact sum of bf16 P used in PV; zero cross-lane).
// Defer-max with LANE-LOCAL trigger: common path has NO cross-lane ops at all.
// K/V double-buffered, counted vmcnt(2); T15 double-pipeline retained (QK(kt+1) || softmax(kt)).
__launch_bounds__(256, 4)
__global__ void attn_k(const short* __restrict__ qb, const short* __restrict__ kb,
                       const short* __restrict__ vtb, float* __restrict__ out) {
  __shared__ short lK[2][64 * 64];    // [kv][d], chunk-XOR swizzled via source
  __shared__ short lVT[2][64 * 64];   // [d][kv], chunk-XOR swizzled via source
  __shared__ short lP[4][16 * 64];    // per-wave P^T as [q][kv], chunk-XOR swizzled
  const int tid = threadIdx.x, l = tid & 63, w = tid >> 6;
  const int l15 = l & 15, lg = l >> 4;

  const int id = blockIdx.x;
  const int bh = (id & 7) * 4 + ((id >> 3) & 3);
  const int qt = id >> 5;

  const short* kbase = kb + bh * 2048 * 64;
  const short* vtbase = vtb + bh * 64 * 2048;

  const int srow = tid >> 3, sch = tid & 7;
  const int gch = sch ^ (srow & 7);
  const short* ksrc = kbase + srow * 64 + gch * 8;     // +kt*4096
  const short* vsrc = vtbase + srow * 2048 + gch * 8;  // +kt*64

  auto stageKV = [&](int buf, int kt) {                // 4 loads/thread: K,K,V,V
    gload_lds16(ksrc + kt * 4096, (char*)lK[buf] + tid * 16);
    gload_lds16(ksrc + kt * 4096 + 2048, (char*)lK[buf] + 4096 + tid * 16);
    gload_lds16(vsrc + kt * 64, (char*)lVT[buf] + tid * 16);
    gload_lds16(vsrc + kt * 64 + 32 * 2048, (char*)lVT[buf] + 4096 + tid * 16);
  };

  // Q B-frag (lane l15 = q column), q pre-scaled by log2e/8
  const int q = qt * 64 + w * 16 + l15;
  const short* qptr = qb + (bh * 2048 + q) * 64;
  short8 qf[2];
  qf[0] = *reinterpret_cast<const short8*>(qptr + lg * 8);
  qf[1] = *reinterpret_cast<const short8*>(qptr + 32 + lg * 8);

  stageKV(0, 0);
  stageKV(1, 1);

  // all-ones A-frag (bf16 1.0) for the sum MFMA
  short8 onesf;
#pragma unroll
  for (int e = 0; e < 8; ++e) onesf[e] = (short)0x3F80;

  f32x4 o[4] = {};
  f32x4 osum = {};
  f32x4 sA[4] = {}, sB[4];
  float mval = -1e30f;
  char* pw = (char*)lP[w];
  const int pbase = l15 * 128;

  // prologue: QK(0) -> sA
  asm volatile("s_waitcnt vmcnt(6)" ::: "memory");
  __builtin_amdgcn_sched_barrier(0);
  __builtin_amdgcn_s_barrier();
  __builtin_amdgcn_sched_barrier(0);
  {
    const char* lk = (const char*)lK[0];
#pragma unroll
    for (int kc = 0; kc < 2; ++kc)
#pragma unroll
      for (int m = 0; m < 4; ++m) {
        int row = m * 16 + l15;
        short8 kf = *reinterpret_cast<const short8*>(lk + row * 128 + (((kc * 4 + lg) ^ (row & 7)) * 16));
        sA[m] = __builtin_amdgcn_mfma_f32_16x16x32_bf16(kf, qf[kc], sA[m], 0, 0, 0);
      }
  }

  auto tile = [&](int kt, f32x4 (&sC)[4], f32x4 (&sN)[4]) {
    // entry: wait V(kt) + K(kt+1) (oldest pairs), leave V(kt+1) in flight
    if (kt == 31) asm volatile("s_waitcnt vmcnt(0)" ::: "memory");
    else          asm volatile("s_waitcnt vmcnt(2)" ::: "memory");
    __builtin_amdgcn_sched_barrier(0);
    __builtin_amdgcn_s_barrier();
    __builtin_amdgcn_sched_barrier(0);

    // QK^T(kt+1) -> sN : matrix pipe, independent of softmax below
    if (kt + 1 < 32) {
      const char* lk = (const char*)lK[(kt + 1) & 1];
      __builtin_amdgcn_s_setprio(1);
#pragma unroll
      for (int m = 0; m < 4; ++m) sN[m] = (f32x4){};
#pragma unroll
      for (int kc = 0; kc < 2; ++kc)
#pragma unroll
        for (int m = 0; m < 4; ++m) {
          int row = m * 16 + l15;
          short8 kf = *reinterpret_cast<const short8*>(lk + row * 128 + (((kc * 4 + lg) ^ (row & 7)) * 16));
          sN[m] = __builtin_amdgcn_mfma_f32_16x16x32_bf16(kf, qf[kc], sN[m], 0, 0, 0);
        }
      __builtin_amdgcn_s_setprio(0);
    }

    // lane-local max (8-op max3-style chain; covers this lane's 16 scores)
    float lm = fmaxf(fmaxf(sC[0][0], sC[0][1]), sC[0][2]);
    lm = fmaxf(fmaxf(lm, sC[0][3]), sC[1][0]);
    lm = fmaxf(fmaxf(lm, sC[1][1]), sC[1][2]);
    lm = fmaxf(fmaxf(lm, sC[1][3]), sC[2][0]);
    lm = fmaxf(fmaxf(lm, sC[2][1]), sC[2][2]);
    lm = fmaxf(fmaxf(lm, sC[2][3]), sC[3][0]);
    lm = fmaxf(fmaxf(lm, sC[3][1]), sC[3][2]);
    lm = fmaxf(lm, sC[3][3]);

    // defer-max, lane-local trigger: common path does NO cross-lane reduce and NO rescale.
    if (!__all(lm <= mval + 8.0f)) {
      float rm = fmaxf(lm, __shfl_xor(lm, 16));
      rm = fmaxf(rm, __shfl_xor(rm, 32));     // true row max (4 lanes share q)
      float mn = fmaxf(mval, rm);
      float corr = fast_exp2(mval - mn);
      mval = mn;
#pragma unroll
      for (int i = 0; i < 4; ++i) osum[i] *= corr;
#pragma unroll
      for (int dt = 0; dt < 4; ++dt)
#pragma unroll
        for (int i = 0; i < 4; ++i) o[dt][i] *= corr;
    }

    // P = 2^(S - m)  (bounded by 2^8 via defer threshold)
#pragma unroll
    for (int m = 0; m < 4; ++m)
#pragma unroll
      for (int i = 0; i < 4; ++i)
        sC[m][i] = fast_exp2(sC[m][i] - mval);

    // pack P -> per-wave LDS (C-frag -> A-frag relayout)
#pragma unroll
    for (int m = 0; m < 4; ++m)
#pragma unroll
      for (int j = 0; j < 2; ++j) {
        unsigned int v32 = cvtpk(sC[m][2 * j], sC[m][2 * j + 1]);
        int kv = m * 16 + lg * 4 + 2 * j;
        *reinterpret_cast<unsigned int*>(
            pw + pbase + (((kv >> 3) ^ (l15 & 7)) * 16) + ((kv & 7) * 2)) = v32;
      }

    // O^T += V^T(kt) P^T(kt);  osum += ones . P^T  (row sum on the matrix pipe)
    const char* lv = (const char*)lVT[kt & 1];
    __builtin_amdgcn_s_setprio(1);
#pragma unroll
    for (int kc = 0; kc < 2; ++kc) {
      short8 pf = *reinterpret_cast<const short8*>(
          pw + pbase + (((kc * 4 + lg) ^ (l15 & 7)) * 16));
      osum = __builtin_amdgcn_mfma_f32_16x16x32_bf16(onesf, pf, osum, 0, 0, 0);
#pragma unroll
      for (int dt = 0; dt < 4; ++dt) {
        int row = dt * 16 + l15;
        short8 vf = *reinterpret_cast<const short8*>(lv + row * 128 + (((kc * 4 + lg) ^ (row & 7)) * 16));
        o[dt] = __builtin_amdgcn_mfma_f32_16x16x32_bf16(vf, pf, o[dt], 0, 0, 0);
      }
    }
    __builtin_amdgcn_s_setprio(0);

    __builtin_amdgcn_sched_barrier(0);
    __builtin_amdgcn_s_barrier();            // all waves done with K(kt)/V(kt) buffers
    __builtin_amdgcn_sched_barrier(0);
    if (kt + 2 < 32) stageKV(kt & 1, kt + 2);  // overwrite just-freed buffer
  };

  for (int kt = 0; kt < 32; kt += 2) {
    tile(kt, sA, sB);
    tile(kt + 1, sB, sA);
  }

  // epilogue: every lane holds its q's sum in osum (all rows identical)
  float inv = 1.0f / osum[0];
  const int b = bh >> 4, h = bh & 15;
  float* op = out + ((b * 2048 + q) * 1024) + h * 64;
#pragma unroll
  for (int dt = 0; dt < 4; ++dt) {
    f32x4 r = { o[dt][0] * inv, o[dt][1] * inv, o[dt][2] * inv, o[dt][3] * inv };
    *reinterpret_cast<f32x4*>(op + dt * 16 + lg * 4) = r;
  }
}

// ---------------- launch ----------------
extern "C" void kernel_launch(void* const* d_in, const int* in_sizes, int n_in,
                              void* d_out, int out_size, void* d_ws, size_t ws_size,
                              hipStream_t stream) {
  const float* x    = (const float*)d_in[0];   // [2,2048,1024]
  const float* W    = (const float*)d_in[1];   // [3072,1024]
  const float* bias = (const float*)d_in[2];   // [3072]
  float* out = (float*)d_out;
  char* ws = (char*)d_ws;

  short*  xb   = (short*) (ws);                  //  8 MiB
  short*  wb   = (short*) (ws + 8388608);        //  6 MiB
  short*  qbuf = (short*) (ws + 14680064);       //  8 MiB q [bh][t][d] (pre-scaled)
  short*  kbuf = (short*) (ws + 23068672);       //  8 MiB k [bh][t][d]
  short*  vtbuf= (short*) (ws + 31457280);       //  8 MiB v TRANSPOSED [bh][d][t]
  float2* tab  = (float2*)(ws + 39845888);       //  512 KiB

  hipLaunchKernelGGL(prep_k, dim3(7424), dim3(256), 0, stream, x, W, xb, wb, tab);
  hipLaunchKernelGGL(qkv_gemm_k, dim3(768), dim3(256), 0, stream,
                     xb, wb, bias, tab, qbuf, kbuf, vtbuf);
  hipLaunchKernelGGL(attn_k, dim3(1024), dim3(256), 0, stream, qbuf, kbuf, vtbuf, out);
}